// Round 1
// baseline (3522.054 us; speedup 1.0000x reference)
//
#include <hip/hip_runtime.h>
#include <hip/hip_bf16.h>
#include <stdint.h>

#define NODES 50000
#define RELS  4
#define EDGES 1600000
#define FEAT  256
#define NCLS  16

static __device__ __forceinline__ float bf2f(unsigned short u) {
    return __uint_as_float(((unsigned int)u) << 16);
}
static __device__ __forceinline__ unsigned short f2bf(float f) {
    unsigned int x = __float_as_uint(f);
    unsigned int r = x + 0x7fffu + ((x >> 16) & 1u);
    return (unsigned short)(r >> 16);
}

// ---------------- CSR build ----------------

__global__ void k_hist(const int* __restrict__ edges, int* deg_row, int* deg_col) {
    int idx = blockIdx.x * blockDim.x + threadIdx.x;
    if (idx >= RELS * EDGES) return;
    int r = idx / EDGES;
    int e = idx - r * EDGES;
    const int* base = edges + (size_t)r * 2 * EDGES;
    int row = base[e];
    int col = base[EDGES + e];
    atomicAdd(&deg_row[r * NODES + row], 1);
    atomicAdd(&deg_col[r * NODES + col], 1);
}

__global__ void k_dinv(const int* __restrict__ deg_row, const int* __restrict__ deg_col,
                       float* dinv_row, float* dinv_col) {
    int idx = blockIdx.x * blockDim.x + threadIdx.x;
    if (idx >= RELS * NODES) return;
    int dr = deg_row[idx]; if (dr < 1) dr = 1;
    int dc = deg_col[idx]; if (dc < 1) dc = 1;
    dinv_row[idx] = rsqrtf((float)dr);
    dinv_col[idx] = rsqrtf((float)dc);
}

// one block per relation; Hillis-Steele chunked exclusive scan of deg_row -> row_ptr, cursor
__global__ void k_scan(const int* __restrict__ deg_row, int* row_ptr, int* cursor) {
    int r = blockIdx.x;
    int tid = threadIdx.x;
    __shared__ int s[1024];
    int carry = 0;
    for (int base = 0; base < NODES; base += 1024) {
        int i = base + tid;
        int v = (i < NODES) ? deg_row[r * NODES + i] : 0;
        s[tid] = v;
        __syncthreads();
        for (int off = 1; off < 1024; off <<= 1) {
            int t = (tid >= off) ? s[tid - off] : 0;
            __syncthreads();
            s[tid] += t;
            __syncthreads();
        }
        int incl = s[tid];
        if (i < NODES) {
            int excl = carry + incl - v;
            row_ptr[r * (NODES + 1) + i] = excl;
            cursor[r * NODES + i] = excl;
        }
        int tot = s[1023];
        __syncthreads();   // protect s[] before next chunk overwrites
        carry += tot;
    }
    if (tid == 0) row_ptr[r * (NODES + 1) + NODES] = carry;
}

__global__ void k_fill(const int* __restrict__ edges, int* cursor, int* csr_col) {
    int idx = blockIdx.x * blockDim.x + threadIdx.x;
    if (idx >= RELS * EDGES) return;
    int r = idx / EDGES;
    int e = idx - r * EDGES;
    const int* base = edges + (size_t)r * 2 * EDGES;
    int row = base[e];
    int col = base[EDGES + e];
    int pos = atomicAdd(&cursor[r * NODES + row], 1);
    csr_col[(size_t)r * EDGES + pos] = col;
}

// ---------------- conversions ----------------

__global__ void k_f2bf(const float* __restrict__ src, unsigned short* __restrict__ dst, int count) {
    int i = blockIdx.x * blockDim.x + threadIdx.x;
    if (i < count) dst[i] = f2bf(src[i]);
}

// ---------------- SPMM: wave per row ----------------

__global__ __launch_bounds__(256)
void k_spmm(const unsigned short* __restrict__ feat, const int* __restrict__ row_ptr,
            const int* __restrict__ csr_col, const float* __restrict__ dinv_row,
            const float* __restrict__ dinv_col, float* __restrict__ agg, int rel) {
    int wave = (blockIdx.x * blockDim.x + threadIdx.x) >> 6;
    int lane = threadIdx.x & 63;
    if (wave >= NODES) return;
    int row = wave;
    int start = row_ptr[rel * (NODES + 1) + row];
    int end   = row_ptr[rel * (NODES + 1) + row + 1];
    const int* cols = csr_col + (size_t)rel * EDGES;
    const float* dc = dinv_col + rel * NODES;
    const unsigned short* fbase = feat + lane * 4;
    float ax = 0.f, ay = 0.f, az = 0.f, aw = 0.f;
    for (int j = start; j < end; ++j) {
        int col = cols[j];
        float wv = dc[col];
        ushort4 u = *(const ushort4*)(fbase + (size_t)col * FEAT);
        ax += wv * bf2f(u.x);
        ay += wv * bf2f(u.y);
        az += wv * bf2f(u.z);
        aw += wv * bf2f(u.w);
    }
    float dr = dinv_row[rel * NODES + row];
    float4 out = { ax * dr, ay * dr, az * dr, aw * dr };
    *(float4*)(agg + (size_t)row * FEAT + lane * 4) = out;
}

// ---------------- GEMM: C = relu(A[50000x256] @ B[256x256]) ----------------
// mode 0: h1 += 0.25*relu(acc)        (fp32 accumulate across 4 relation launches)
// mode 1: H2bf[rel] = bf16(relu(acc))

#define BM 64
#define BN 64
#define BK 16

__global__ __launch_bounds__(256)
void k_gemm(const float* __restrict__ A, const float* __restrict__ B,
            float* __restrict__ h1, unsigned short* __restrict__ H2bf, int rel, int mode) {
    __shared__ float As[BK][BM + 4];
    __shared__ float Bs[BK][BN + 4];
    int tid = threadIdx.x;
    int tx = tid & 15, ty = tid >> 4;
    int row0 = blockIdx.x * BM, col0 = blockIdx.y * BN;

    float acc[4][4] = {{0.f}};

    int am = tid >> 2;            // 0..63
    int ak = (tid & 3) * 4;       // 0,4,8,12
    int br = tid >> 4;            // 0..15
    int bc = (tid & 15) * 4;      // 0..60

    for (int k0 = 0; k0 < FEAT; k0 += BK) {
        int arow = row0 + am;
        float4 av;
        if (arow < NODES) av = *(const float4*)(A + (size_t)arow * FEAT + k0 + ak);
        else { av.x = av.y = av.z = av.w = 0.f; }
        As[ak + 0][am] = av.x;
        As[ak + 1][am] = av.y;
        As[ak + 2][am] = av.z;
        As[ak + 3][am] = av.w;
        float4 bv = *(const float4*)(B + (size_t)(k0 + br) * FEAT + col0 + bc);
        *(float4*)&Bs[br][bc] = bv;
        __syncthreads();
#pragma unroll
        for (int kk = 0; kk < BK; ++kk) {
            float4 a = *(const float4*)&As[kk][ty * 4];
            float4 b = *(const float4*)&Bs[kk][tx * 4];
            acc[0][0] += a.x * b.x; acc[0][1] += a.x * b.y; acc[0][2] += a.x * b.z; acc[0][3] += a.x * b.w;
            acc[1][0] += a.y * b.x; acc[1][1] += a.y * b.y; acc[1][2] += a.y * b.z; acc[1][3] += a.y * b.w;
            acc[2][0] += a.z * b.x; acc[2][1] += a.z * b.y; acc[2][2] += a.z * b.z; acc[2][3] += a.z * b.w;
            acc[3][0] += a.w * b.x; acc[3][1] += a.w * b.y; acc[3][2] += a.w * b.z; acc[3][3] += a.w * b.w;
        }
        __syncthreads();
    }

#pragma unroll
    for (int i = 0; i < 4; ++i) {
        int m = row0 + ty * 4 + i;
        if (m >= NODES) continue;
#pragma unroll
        for (int j = 0; j < 4; ++j) {
            float v = acc[i][j];
            v = v > 0.f ? v : 0.f;
            int n = col0 + tx * 4 + j;
            if (mode == 0) {
                h1[(size_t)m * FEAT + n] += 0.25f * v;
            } else {
                H2bf[((size_t)rel * NODES + m) * FEAT + n] = f2bf(v);
            }
        }
    }
}

// ---------------- attention scores + softmax (wave per node) ----------------

__global__ __launch_bounds__(256)
void k_scores(const unsigned short* __restrict__ H2bf, const float* __restrict__ att_q,
              const float* __restrict__ tau_p, float* __restrict__ alpha_out) {
    int wave = (blockIdx.x * blockDim.x + threadIdx.x) >> 6;
    int lane = threadIdx.x & 63;
    if (wave >= NODES) return;
    int n = wave;
    float4 q = *(const float4*)(att_q + lane * 4);
    float s[RELS];
#pragma unroll
    for (int r = 0; r < RELS; ++r) {
        ushort4 u = *(const ushort4*)(H2bf + ((size_t)r * NODES + n) * FEAT + lane * 4);
        s[r] = bf2f(u.x) * q.x + bf2f(u.y) * q.y + bf2f(u.z) * q.z + bf2f(u.w) * q.w;
    }
#pragma unroll
    for (int off = 32; off > 0; off >>= 1) {
#pragma unroll
        for (int r = 0; r < RELS; ++r) s[r] += __shfl_down(s[r], off, 64);
    }
    if (lane == 0) {
        float tau = tau_p[0];
        tau = fminf(fmaxf(tau, 0.5f), 5.0f);
        float it = 1.0f / tau;
        float m = fmaxf(fmaxf(s[0], s[1]), fmaxf(s[2], s[3]));
        float e0 = expf((s[0] - m) * it);
        float e1 = expf((s[1] - m) * it);
        float e2 = expf((s[2] - m) * it);
        float e3 = expf((s[3] - m) * it);
        float inv = 1.0f / (e0 + e1 + e2 + e3);
        float4 al = { e0 * inv, e1 * inv, e2 * inv, e3 * inv };
        *(float4*)(alpha_out + (size_t)n * 4) = al;
    }
}

// ---------------- fused h2-combine + output GEMM ----------------
// thread per (n, c): logits[n][c] = b_out[c] + sum_h (sum_r (0.25+alpha_nr)*H2_r[n][h]) * W_out[h][c]

__global__ __launch_bounds__(256)
void k_logits(const unsigned short* __restrict__ H2bf, const float* __restrict__ alpha,
              const float* __restrict__ W_out, const float* __restrict__ b_out,
              float* __restrict__ logits) {
    int gid = blockIdx.x * blockDim.x + threadIdx.x;
    if (gid >= NODES * NCLS) return;
    int n = gid >> 4;
    int c = gid & 15;
    float a0 = 0.25f + alpha[(size_t)n * 4 + 0];
    float a1 = 0.25f + alpha[(size_t)n * 4 + 1];
    float a2 = 0.25f + alpha[(size_t)n * 4 + 2];
    float a3 = 0.25f + alpha[(size_t)n * 4 + 3];
    const unsigned short* h0 = H2bf + (size_t)n * FEAT;
    const size_t rs = (size_t)NODES * FEAT;
    float acc = b_out[c];
#pragma unroll 4
    for (int h = 0; h < FEAT; ++h) {
        float h2 = a0 * bf2f(h0[h]) + a1 * bf2f(h0[h + rs]) +
                   a2 * bf2f(h0[h + 2 * rs]) + a3 * bf2f(h0[h + 3 * rs]);
        acc += h2 * W_out[h * NCLS + c];
    }
    logits[gid] = acc;
}

// ---------------- launcher ----------------

static inline int cdiv(int a, int b) { return (a + b - 1) / b; }

extern "C" void kernel_launch(void* const* d_in, const int* in_sizes, int n_in,
                              void* d_out, int out_size, void* d_ws, size_t ws_size,
                              hipStream_t stream) {
    const float* X     = (const float*)d_in[0];
    const int*   edges = (const int*)d_in[1];
    const float* W1    = (const float*)d_in[2];
    const float* W2    = (const float*)d_in[3];
    const float* att_q = (const float*)d_in[4];
    const float* tau   = (const float*)d_in[5];
    const float* W_out = (const float*)d_in[6];
    const float* b_out = (const float*)d_in[7];

    float* logits = (float*)d_out;
    float* alpha  = logits + (size_t)NODES * NCLS;

    // workspace arena (~235 MB)
    char* p = (char*)d_ws;
    auto carve = [&](size_t bytes) -> char* {
        char* q = p;
        p += (bytes + 255) & ~(size_t)255;
        return q;
    };
    int*   deg_row  = (int*)carve((size_t)RELS * NODES * 4);
    int*   deg_col  = (int*)carve((size_t)RELS * NODES * 4);
    float* dinv_row = (float*)carve((size_t)RELS * NODES * 4);
    float* dinv_col = (float*)carve((size_t)RELS * NODES * 4);
    int*   row_ptr  = (int*)carve((size_t)RELS * (NODES + 1) * 4);
    int*   cursor   = (int*)carve((size_t)RELS * NODES * 4);
    int*   csr_col  = (int*)carve((size_t)RELS * EDGES * 4);
    unsigned short* Xbf  = (unsigned short*)carve((size_t)NODES * FEAT * 2);
    unsigned short* h1bf = (unsigned short*)carve((size_t)NODES * FEAT * 2);
    float* agg = (float*)carve((size_t)NODES * FEAT * 4);
    unsigned short* H2bf = (unsigned short*)carve((size_t)RELS * NODES * FEAT * 2);
    // h1 fp32 aliases the H2bf region (H2bf is only written after h1 is consumed)
    float* h1f = (float*)H2bf;

    // zero the accumulators (deg_row/deg_col are contiguous: one memset)
    hipMemsetAsync(deg_row, 0, (size_t)2 * RELS * NODES * 4, stream);
    hipMemsetAsync(h1f, 0, (size_t)NODES * FEAT * 4, stream);

    // CSR build
    k_hist<<<cdiv(RELS * EDGES, 256), 256, 0, stream>>>(edges, deg_row, deg_col);
    k_dinv<<<cdiv(RELS * NODES, 256), 256, 0, stream>>>(deg_row, deg_col, dinv_row, dinv_col);
    k_scan<<<RELS, 1024, 0, stream>>>(deg_row, row_ptr, cursor);
    k_fill<<<cdiv(RELS * EDGES, 256), 256, 0, stream>>>(edges, cursor, csr_col);

    // X -> bf16
    k_f2bf<<<cdiv(NODES * FEAT, 256), 256, 0, stream>>>(X, Xbf, NODES * FEAT);

    dim3 gemm_grid(cdiv(NODES, BM), FEAT / BN);

    // Layer 1: h1 = mean_r relu(SPMM_r(X) @ W1_r)
    for (int r = 0; r < RELS; ++r) {
        k_spmm<<<cdiv(NODES * 64, 256), 256, 0, stream>>>(Xbf, row_ptr, csr_col,
                                                          dinv_row, dinv_col, agg, r);
        k_gemm<<<gemm_grid, 256, 0, stream>>>(agg, W1 + (size_t)r * FEAT * FEAT,
                                              h1f, nullptr, r, 0);
    }
    // h1 -> bf16
    k_f2bf<<<cdiv(NODES * FEAT, 256), 256, 0, stream>>>(h1f, h1bf, NODES * FEAT);

    // Layer 2: H2_r = relu(SPMM_r(h1) @ W2_r), stored bf16
    for (int r = 0; r < RELS; ++r) {
        k_spmm<<<cdiv(NODES * 64, 256), 256, 0, stream>>>(h1bf, row_ptr, csr_col,
                                                          dinv_row, dinv_col, agg, r);
        k_gemm<<<gemm_grid, 256, 0, stream>>>(agg, W2 + (size_t)r * FEAT * FEAT,
                                              nullptr, H2bf, r, 1);
    }

    // attention + output
    k_scores<<<cdiv(NODES * 64, 256), 256, 0, stream>>>(H2bf, att_q, tau, alpha);
    k_logits<<<cdiv(NODES * NCLS, 256), 256, 0, stream>>>(H2bf, alpha, W_out, b_out, logits);
}

// Round 2
// 3169.014 us; speedup vs baseline: 1.1114x; 1.1114x over previous
//
#include <hip/hip_runtime.h>
#include <hip/hip_bf16.h>
#include <stdint.h>

#define NODES 50000
#define RELS  4
#define EDGES 1600000
#define FEAT  256
#define NCLS  16
#define MPAD  50048   // 391 * 128

typedef __attribute__((ext_vector_type(8))) short short8;
typedef __attribute__((ext_vector_type(4))) float f32x4;

static __device__ __forceinline__ float bf2f(unsigned short u) {
    return __uint_as_float(((unsigned int)u) << 16);
}
static __device__ __forceinline__ unsigned short f2bf(float f) {
    unsigned int x = __float_as_uint(f);
    unsigned int r = x + 0x7fffu + ((x >> 16) & 1u);
    return (unsigned short)(r >> 16);
}

// ---------------- CSR build ----------------

__global__ void k_hist(const int* __restrict__ edges, int* deg_row, int* deg_col) {
    int idx = blockIdx.x * blockDim.x + threadIdx.x;
    if (idx >= RELS * EDGES) return;
    int r = idx / EDGES;
    int e = idx - r * EDGES;
    const int* base = edges + (size_t)r * 2 * EDGES;
    int row = base[e];
    int col = base[EDGES + e];
    atomicAdd(&deg_row[r * NODES + row], 1);
    atomicAdd(&deg_col[r * NODES + col], 1);
}

__global__ void k_dinv(const int* __restrict__ deg_row, const int* __restrict__ deg_col,
                       float* dinv_row, float* dinv_col) {
    int idx = blockIdx.x * blockDim.x + threadIdx.x;
    if (idx >= RELS * NODES) return;
    int dr = deg_row[idx]; if (dr < 1) dr = 1;
    int dc = deg_col[idx]; if (dc < 1) dc = 1;
    dinv_row[idx] = rsqrtf((float)dr);
    dinv_col[idx] = rsqrtf((float)dc);
}

// one block per relation; Hillis-Steele chunked exclusive scan of deg_row -> row_ptr, cursor
__global__ void k_scan(const int* __restrict__ deg_row, int* row_ptr, int* cursor) {
    int r = blockIdx.x;
    int tid = threadIdx.x;
    __shared__ int s[1024];
    int carry = 0;
    for (int base = 0; base < NODES; base += 1024) {
        int i = base + tid;
        int v = (i < NODES) ? deg_row[r * NODES + i] : 0;
        s[tid] = v;
        __syncthreads();
        for (int off = 1; off < 1024; off <<= 1) {
            int t = (tid >= off) ? s[tid - off] : 0;
            __syncthreads();
            s[tid] += t;
            __syncthreads();
        }
        int incl = s[tid];
        if (i < NODES) {
            int excl = carry + incl - v;
            row_ptr[r * (NODES + 1) + i] = excl;
            cursor[r * NODES + i] = excl;
        }
        int tot = s[1023];
        __syncthreads();
        carry += tot;
    }
    if (tid == 0) row_ptr[r * (NODES + 1) + NODES] = carry;
}

__global__ void k_fill(const int* __restrict__ edges, int* cursor, int* csr_col) {
    int idx = blockIdx.x * blockDim.x + threadIdx.x;
    if (idx >= RELS * EDGES) return;
    int r = idx / EDGES;
    int e = idx - r * EDGES;
    const int* base = edges + (size_t)r * 2 * EDGES;
    int row = base[e];
    int col = base[EDGES + e];
    int pos = atomicAdd(&cursor[r * NODES + row], 1);
    csr_col[(size_t)r * EDGES + pos] = col;
}

// ---------------- conversions ----------------

__global__ void k_f2bf(const float* __restrict__ src, unsigned short* __restrict__ dst, int count) {
    int i = blockIdx.x * blockDim.x + threadIdx.x;
    if (i < count) dst[i] = f2bf(src[i]);
}

// transpose+convert: W[r][k][n] fp32 -> Wt[r][n][k] bf16
__global__ void k_wt(const float* __restrict__ W, unsigned short* __restrict__ Wt) {
    int idx = blockIdx.x * blockDim.x + threadIdx.x;
    if (idx >= RELS * FEAT * FEAT) return;
    int r = idx >> 16;
    int rem = idx & 65535;
    int n = rem >> 8;
    int k = rem & 255;
    Wt[idx] = f2bf(W[(size_t)r * FEAT * FEAT + (size_t)k * FEAT + n]);
}

// ---------------- SPMM: wave per row, bf16 output ----------------

__global__ __launch_bounds__(256)
void k_spmm(const unsigned short* __restrict__ feat, const int* __restrict__ row_ptr,
            const int* __restrict__ csr_col, const float* __restrict__ dinv_row,
            const float* __restrict__ dinv_col, unsigned short* __restrict__ aggbf, int rel) {
    int wave = (blockIdx.x * blockDim.x + threadIdx.x) >> 6;
    int lane = threadIdx.x & 63;
    if (wave >= NODES) return;
    int row = wave;
    int start = row_ptr[rel * (NODES + 1) + row];
    int end   = row_ptr[rel * (NODES + 1) + row + 1];
    const int* cols = csr_col + (size_t)rel * EDGES;
    const float* dc = dinv_col + rel * NODES;
    const unsigned short* fbase = feat + lane * 4;
    float ax = 0.f, ay = 0.f, az = 0.f, aw = 0.f;
    for (int j = start; j < end; ++j) {
        int col = cols[j];
        float wv = dc[col];
        ushort4 u = *(const ushort4*)(fbase + (size_t)col * FEAT);
        ax += wv * bf2f(u.x);
        ay += wv * bf2f(u.y);
        az += wv * bf2f(u.z);
        aw += wv * bf2f(u.w);
    }
    float dr = dinv_row[rel * NODES + row];
    ushort4 out = { f2bf(ax * dr), f2bf(ay * dr), f2bf(az * dr), f2bf(aw * dr) };
    *(ushort4*)(aggbf + (size_t)row * FEAT + lane * 4) = out;
}

// ---------------- MFMA GEMM: C = relu(A[MPAD x 256]bf16 @ Bt^T[256 x 256]bf16) ----------------
// Bt is B^T stored [n][k]. 128x128 tile, BK=64, XOR-swizzled LDS (conflict-free b128).
// mode 0: h1 += 0.25*relu(acc)   mode 1: H2[row*256+col] = bf16(relu(acc))

__global__ __launch_bounds__(256)
void k_gemm_mfma(const unsigned short* __restrict__ A, const unsigned short* __restrict__ Bt,
                 float* __restrict__ h1, unsigned short* __restrict__ H2, int mode) {
    __shared__ __align__(16) unsigned short As[128 * 64];
    __shared__ __align__(16) unsigned short Bs[128 * 64];
    int tid = threadIdx.x;
    int wave = tid >> 6, lane = tid & 63;
    int quad = lane >> 4, l16 = lane & 15;
    int wm = (wave & 1) * 64, wn = (wave >> 1) * 64;
    int row0 = blockIdx.x * 128, n0 = blockIdx.y * 128;

    f32x4 acc[4][4];
#pragma unroll
    for (int mi = 0; mi < 4; ++mi)
#pragma unroll
        for (int ni = 0; ni < 4; ++ni)
            acc[mi][ni] = (f32x4){0.f, 0.f, 0.f, 0.f};

    for (int k0 = 0; k0 < FEAT; k0 += 64) {
        // stage A and Bt tiles, XOR-swizzled on the 16B granule
#pragma unroll
        for (int issue = 0; issue < 4; ++issue) {
            int flat = issue * 256 + tid;          // 0..1023
            int row = flat >> 3;                   // 0..127
            int gr = flat & 7;                     // dest granule
            int sg = gr ^ (row & 7);               // src granule
            *(uint4*)&As[flat * 8] = *(const uint4*)(A + (size_t)(row0 + row) * FEAT + k0 + sg * 8);
            *(uint4*)&Bs[flat * 8] = *(const uint4*)(Bt + (size_t)(n0 + row) * FEAT + k0 + sg * 8);
        }
        __syncthreads();
#pragma unroll
        for (int ks = 0; ks < 2; ++ks) {
            int g = ks * 4 + quad;
            short8 af[4], bfr[4];
#pragma unroll
            for (int mi = 0; mi < 4; ++mi) {
                int m = wm + mi * 16 + l16;
                af[mi] = *(const short8*)&As[m * 64 + ((g ^ (m & 7)) << 3)];
            }
#pragma unroll
            for (int ni = 0; ni < 4; ++ni) {
                int n = wn + ni * 16 + l16;
                bfr[ni] = *(const short8*)&Bs[n * 64 + ((g ^ (n & 7)) << 3)];
            }
#pragma unroll
            for (int mi = 0; mi < 4; ++mi)
#pragma unroll
                for (int ni = 0; ni < 4; ++ni)
                    acc[mi][ni] = __builtin_amdgcn_mfma_f32_16x16x32_bf16(af[mi], bfr[ni], acc[mi][ni], 0, 0, 0);
        }
        __syncthreads();
    }

    // epilogue: C/D layout col=lane&15, row=quad*4+reg
#pragma unroll
    for (int mi = 0; mi < 4; ++mi) {
#pragma unroll
        for (int ni = 0; ni < 4; ++ni) {
            int col = n0 + wn + ni * 16 + l16;
#pragma unroll
            for (int i = 0; i < 4; ++i) {
                int row = row0 + wm + mi * 16 + quad * 4 + i;
                if (row < NODES) {
                    float v = acc[mi][ni][i];
                    v = v > 0.f ? v : 0.f;
                    if (mode == 0) h1[(size_t)row * FEAT + col] += 0.25f * v;
                    else           H2[(size_t)row * FEAT + col] = f2bf(v);
                }
            }
        }
    }
}

// ---------------- attention scores + softmax (wave per node) ----------------

__global__ __launch_bounds__(256)
void k_scores(const unsigned short* __restrict__ H2bf, const float* __restrict__ att_q,
              const float* __restrict__ tau_p, float* __restrict__ alpha_out) {
    int wave = (blockIdx.x * blockDim.x + threadIdx.x) >> 6;
    int lane = threadIdx.x & 63;
    if (wave >= NODES) return;
    int n = wave;
    float4 q = *(const float4*)(att_q + lane * 4);
    float s[RELS];
#pragma unroll
    for (int r = 0; r < RELS; ++r) {
        ushort4 u = *(const ushort4*)(H2bf + ((size_t)r * NODES + n) * FEAT + lane * 4);
        s[r] = bf2f(u.x) * q.x + bf2f(u.y) * q.y + bf2f(u.z) * q.z + bf2f(u.w) * q.w;
    }
#pragma unroll
    for (int off = 32; off > 0; off >>= 1) {
#pragma unroll
        for (int r = 0; r < RELS; ++r) s[r] += __shfl_down(s[r], off, 64);
    }
    if (lane == 0) {
        float tau = tau_p[0];
        tau = fminf(fmaxf(tau, 0.5f), 5.0f);
        float it = 1.0f / tau;
        float m = fmaxf(fmaxf(s[0], s[1]), fmaxf(s[2], s[3]));
        float e0 = expf((s[0] - m) * it);
        float e1 = expf((s[1] - m) * it);
        float e2 = expf((s[2] - m) * it);
        float e3 = expf((s[3] - m) * it);
        float inv = 1.0f / (e0 + e1 + e2 + e3);
        float4 al = { e0 * inv, e1 * inv, e2 * inv, e3 * inv };
        *(float4*)(alpha_out + (size_t)n * 4) = al;
    }
}

// ---------------- fused h2-combine + output GEMM ----------------

__global__ __launch_bounds__(256)
void k_logits(const unsigned short* __restrict__ H2bf, const float* __restrict__ alpha,
              const float* __restrict__ W_out, const float* __restrict__ b_out,
              float* __restrict__ logits) {
    int gid = blockIdx.x * blockDim.x + threadIdx.x;
    if (gid >= NODES * NCLS) return;
    int n = gid >> 4;
    int c = gid & 15;
    float a0 = 0.25f + alpha[(size_t)n * 4 + 0];
    float a1 = 0.25f + alpha[(size_t)n * 4 + 1];
    float a2 = 0.25f + alpha[(size_t)n * 4 + 2];
    float a3 = 0.25f + alpha[(size_t)n * 4 + 3];
    const unsigned short* h0 = H2bf + (size_t)n * FEAT;
    const size_t rs = (size_t)NODES * FEAT;
    float acc = b_out[c];
#pragma unroll 4
    for (int h = 0; h < FEAT; ++h) {
        float h2 = a0 * bf2f(h0[h]) + a1 * bf2f(h0[h + rs]) +
                   a2 * bf2f(h0[h + 2 * rs]) + a3 * bf2f(h0[h + 3 * rs]);
        acc += h2 * W_out[h * NCLS + c];
    }
    logits[gid] = acc;
}

// ---------------- launcher ----------------

static inline int cdiv(int a, int b) { return (a + b - 1) / b; }

extern "C" void kernel_launch(void* const* d_in, const int* in_sizes, int n_in,
                              void* d_out, int out_size, void* d_ws, size_t ws_size,
                              hipStream_t stream) {
    const float* X     = (const float*)d_in[0];
    const int*   edges = (const int*)d_in[1];
    const float* W1    = (const float*)d_in[2];
    const float* W2    = (const float*)d_in[3];
    const float* att_q = (const float*)d_in[4];
    const float* tau   = (const float*)d_in[5];
    const float* W_out = (const float*)d_in[6];
    const float* b_out = (const float*)d_in[7];

    float* logits = (float*)d_out;
    float* alpha  = logits + (size_t)NODES * NCLS;

    char* p = (char*)d_ws;
    auto carve = [&](size_t bytes) -> char* {
        char* q = p;
        p += (bytes + 255) & ~(size_t)255;
        return q;
    };
    int*   deg_row  = (int*)carve((size_t)RELS * NODES * 4);
    int*   deg_col  = (int*)carve((size_t)RELS * NODES * 4);
    float* dinv_row = (float*)carve((size_t)RELS * NODES * 4);
    float* dinv_col = (float*)carve((size_t)RELS * NODES * 4);
    int*   row_ptr  = (int*)carve((size_t)RELS * (NODES + 1) * 4);
    int*   cursor   = (int*)carve((size_t)RELS * NODES * 4);
    int*   csr_col  = (int*)carve((size_t)RELS * EDGES * 4);
    unsigned short* Xbf  = (unsigned short*)carve((size_t)NODES * FEAT * 2);
    unsigned short* h1bf = (unsigned short*)carve((size_t)NODES * FEAT * 2);
    unsigned short* aggbf = (unsigned short*)carve((size_t)MPAD * FEAT * 2);  // padded for 128-tiles
    unsigned short* W1t  = (unsigned short*)carve((size_t)RELS * FEAT * FEAT * 2);
    unsigned short* W2t  = (unsigned short*)carve((size_t)RELS * FEAT * FEAT * 2);
    unsigned short* H2bf = (unsigned short*)carve((size_t)RELS * NODES * FEAT * 2);
    // h1 fp32 aliases the H2bf region (H2bf is only written after h1 is consumed)
    float* h1f = (float*)H2bf;

    hipMemsetAsync(deg_row, 0, (size_t)2 * RELS * NODES * 4, stream);
    hipMemsetAsync(h1f, 0, (size_t)NODES * FEAT * 4, stream);

    // CSR build
    k_hist<<<cdiv(RELS * EDGES, 256), 256, 0, stream>>>(edges, deg_row, deg_col);
    k_dinv<<<cdiv(RELS * NODES, 256), 256, 0, stream>>>(deg_row, deg_col, dinv_row, dinv_col);
    k_scan<<<RELS, 1024, 0, stream>>>(deg_row, row_ptr, cursor);
    k_fill<<<cdiv(RELS * EDGES, 256), 256, 0, stream>>>(edges, cursor, csr_col);

    // conversions
    k_f2bf<<<cdiv(NODES * FEAT, 256), 256, 0, stream>>>(X, Xbf, NODES * FEAT);
    k_wt<<<cdiv(RELS * FEAT * FEAT, 256), 256, 0, stream>>>(W1, W1t);
    k_wt<<<cdiv(RELS * FEAT * FEAT, 256), 256, 0, stream>>>(W2, W2t);

    dim3 gemm_grid(MPAD / 128, FEAT / 128);

    // Layer 1: h1 = mean_r relu(SPMM_r(X) @ W1_r)
    for (int r = 0; r < RELS; ++r) {
        k_spmm<<<cdiv(NODES * 64, 256), 256, 0, stream>>>(Xbf, row_ptr, csr_col,
                                                          dinv_row, dinv_col, aggbf, r);
        k_gemm_mfma<<<gemm_grid, 256, 0, stream>>>(aggbf, W1t + (size_t)r * FEAT * FEAT,
                                                   h1f, nullptr, 0);
    }
    k_f2bf<<<cdiv(NODES * FEAT, 256), 256, 0, stream>>>(h1f, h1bf, NODES * FEAT);

    // Layer 2: H2_r = relu(SPMM_r(h1) @ W2_r), stored bf16
    for (int r = 0; r < RELS; ++r) {
        k_spmm<<<cdiv(NODES * 64, 256), 256, 0, stream>>>(h1bf, row_ptr, csr_col,
                                                          dinv_row, dinv_col, aggbf, r);
        k_gemm_mfma<<<gemm_grid, 256, 0, stream>>>(aggbf, W2t + (size_t)r * FEAT * FEAT,
                                                   nullptr, H2bf + (size_t)r * NODES * FEAT, 1);
    }

    // attention + output
    k_scores<<<cdiv(NODES * 64, 256), 256, 0, stream>>>(H2bf, att_q, tau, alpha);
    k_logits<<<cdiv(NODES * NCLS, 256), 256, 0, stream>>>(H2bf, alpha, W_out, b_out, logits);
}